// Round 4
// baseline (617.191 us; speedup 1.0000x reference)
//
#include <hip/hip_runtime.h>

// ---------- types ----------
typedef __attribute__((ext_vector_type(4))) float   float4_;
typedef __attribute__((ext_vector_type(4))) unsigned short ushort4_;
typedef __attribute__((ext_vector_type(8))) __bf16  bf16x8;
typedef __attribute__((ext_vector_type(4))) float   f32x4;

#define NROWS 8192
#define NKEYS 16384
#define DDIM  256

// exp(x/T) == exp2(x * C_SC)
static constexpr float T_INV = (float)(1.0 / 0.07);
static constexpr float C_SC  = (float)(1.0 / (0.07 * 0.6931471805599453));

__device__ __forceinline__ unsigned short f2bf(float x) {
  union { float f; unsigned int u; } v; v.f = x;
  unsigned int r = v.u + 0x7fffu + ((v.u >> 16) & 1u);   // RNE
  return (unsigned short)(r >> 16);
}
__device__ __forceinline__ float bf2f(unsigned short u) {
  union { unsigned int u; float f; } v; v.u = ((unsigned int)u) << 16; return v.f;
}

// ---------------------------------------------------------------------------
// Kernel 1: normalize rows, emit (ALL natural layouts); also zeroes S.
//   qs   [8192][256] bf16 : normalized q scaled by C_SC (MFMA A operand)
//   keys [16384][256] bf16: rows 0..8191 = q (unscaled), 8192.. = g (unscaled)
//   Pterm[row]   = dot(q,g)/T (fp32)
//   diagsub[row] = exp2(dot_fp32(qs_bf16, q_bf16))  — bf16-level qq diagonal
// ---------------------------------------------------------------------------
__global__ __launch_bounds__(64) void prep_kernel(
    const float* __restrict__ h, const float* __restrict__ g,
    unsigned short* __restrict__ qs, unsigned short* __restrict__ keys,
    float* __restrict__ Pterm, float* __restrict__ diagsub,
    float* __restrict__ S)
{
  const int row  = blockIdx.x;
  const int lane = threadIdx.x;            // 0..63, 4 dims each
  float4_ hv = *((const float4_*)h + row * 64 + lane);
  float4_ gv = *((const float4_*)g + row * 64 + lane);

  float ssh = hv.x*hv.x + hv.y*hv.y + hv.z*hv.z + hv.w*hv.w;
  float ssg = gv.x*gv.x + gv.y*gv.y + gv.z*gv.z + gv.w*gv.w;
#pragma unroll
  for (int m = 1; m < 64; m <<= 1) {
    ssh += __shfl_xor(ssh, m);
    ssg += __shfl_xor(ssg, m);
  }
  const float sh = 1.0f / fmaxf(sqrtf(ssh), 1e-8f);
  const float sg = 1.0f / fmaxf(sqrtf(ssg), 1e-8f);

  float qn[4] = { hv.x*sh, hv.y*sh, hv.z*sh, hv.w*sh };
  float gn[4] = { gv.x*sg, gv.y*sg, gv.z*sg, gv.w*sg };

  float pd = qn[0]*gn[0] + qn[1]*gn[1] + qn[2]*gn[2] + qn[3]*gn[3];

  unsigned short qb[4], qsb[4], gb[4];
  float dd = 0.0f;
#pragma unroll
  for (int j = 0; j < 4; ++j) {
    qb[j]  = f2bf(qn[j]);
    qsb[j] = f2bf(qn[j] * C_SC);
    gb[j]  = f2bf(gn[j]);
    dd += bf2f(qsb[j]) * bf2f(qb[j]);
  }
#pragma unroll
  for (int m = 1; m < 64; m <<= 1) {
    pd += __shfl_xor(pd, m);
    dd += __shfl_xor(dd, m);
  }

  ushort4_ vqs = { qsb[0], qsb[1], qsb[2], qsb[3] };
  ushort4_ vq  = { qb[0],  qb[1],  qb[2],  qb[3]  };
  ushort4_ vg  = { gb[0],  gb[1],  gb[2],  gb[3]  };
  *((ushort4_*)qs   + (size_t)row * 64 + lane)           = vqs;
  *((ushort4_*)keys + (size_t)row * 64 + lane)           = vq;
  *((ushort4_*)keys + (size_t)(NROWS + row) * 64 + lane) = vg;

  if (lane == 0) {
    Pterm[row]   = pd * T_INV;
    diagsub[row] = __builtin_amdgcn_exp2f(dd);
    S[row]       = 0.0f;                   // replaces the memset dispatch
  }
}

// ---------------------------------------------------------------------------
// Kernel 2: fused GEMM + exp2 + row-sum.
// Grid 512 = 64 M-tiles (BM=128) x 8 key-slices (2048 keys each).
// slice = bid & 7  -> each XCD owns exactly one 1MB slice (L2-resident).
// 2 blocks/CU resident (64KB LDS) -> 16 waves/CU for phase overlap.
// 8 waves (2m x 4n); Q frags in registers; keys reg-staged into double-
// buffered LDS with XOR swizzle applied at ds_write and undone at ds_read
// through the SAME lds_off(). Per-wave kk-stagger spreads LDS-read and
// MFMA bursts; setprio(1) keeps the matrix pipe fed (T5).
// ---------------------------------------------------------------------------
__device__ __forceinline__ int lds_off(int r, int g) {   // elements
  return r * DDIM + (((g ^ (r & 7)) & 31) << 3);
}

__global__ __launch_bounds__(512, 2) void nce_gemm(
    const unsigned short* __restrict__ qs,
    const unsigned short* __restrict__ keys,
    float* __restrict__ S)
{
  __shared__ __align__(16) unsigned short lds_k[2 * 64 * DDIM]; // 64 KB

  const int tid  = threadIdx.x;
  const int wid  = tid >> 6;
  const int lane = tid & 63;
  const int l15  = lane & 15, l4 = lane >> 4;

  const int bid   = blockIdx.x;
  const int slice = bid & 7;               // == XCD id: slice L2-resident
  const int mtile = bid >> 3;              // 0..63

  const int wm = wid >> 2;                 // 0..1
  const int wn = wid & 3;                  // 0..3
  const int m0 = mtile * 128 + wm * 64;

  // ---- Q fragments into registers (natural layout, pre-scaled by C_SC) ----
  bf16x8 a[4][8];
#pragma unroll
  for (int mf = 0; mf < 4; ++mf) {
    const unsigned short* rp = qs + (size_t)(m0 + mf * 16 + l15) * DDIM + l4 * 8;
#pragma unroll
    for (int kk = 0; kk < 8; ++kk)
      a[mf][kk] = *(const bf16x8*)(rp + kk * 32);
  }

  const f32x4 zero4 = { 0.f, 0.f, 0.f, 0.f };
  f32x4 acc[4] = { zero4, zero4, zero4, zero4 };
  float Sp[4][4] = {};

  // staging map: thread t -> key-row sr = t>>3, groups (t&7)+8u, u=0..3
  const int sr  = tid >> 3;                // 0..63
  const int sg0 = tid & 7;
  const unsigned short* kslice = keys + (size_t)slice * 2048 * DDIM;

  bf16x8 stg[4];
  auto load_chunk = [&](int c) {
    const unsigned short* base = kslice + ((size_t)c * 64 + sr) * DDIM;
#pragma unroll
    for (int u = 0; u < 4; ++u)
      stg[u] = *(const bf16x8*)(base + ((sg0 + 8 * u) << 3));
  };
  auto write_chunk = [&](int buf) {
    unsigned short* dst = lds_k + buf * (64 * DDIM);
#pragma unroll
    for (int u = 0; u < 4; ++u)
      *(bf16x8*)(dst + lds_off(sr, sg0 + 8 * u)) = stg[u];
  };

  load_chunk(0);
  for (int c = 0; c < 32; ++c) {
    const int buf = c & 1;
    write_chunk(buf);
    __syncthreads();                       // LDS writes visible; dbuf-safe
    if (c + 1 < 32) load_chunk(c + 1);     // in flight across whole chunk

    const unsigned short* lb = lds_k + buf * (64 * DDIM);
#pragma unroll
    for (int j = 0; j < 8; ++j) {
      const int kk = (j + wid) & 7;        // per-wave stagger (sum-invariant)
      bf16x8 b = *(const bf16x8*)(lb + lds_off(wn * 16 + l15, kk * 4 + l4));
      __builtin_amdgcn_s_setprio(1);
#pragma unroll
      for (int mf = 0; mf < 4; ++mf)
        acc[mf] = __builtin_amdgcn_mfma_f32_16x16x32_bf16(a[mf][kk], b, acc[mf], 0, 0, 0);
      __builtin_amdgcn_s_setprio(0);
    }
    // harvest: D layout (m89): col = lane&15, row = (lane>>4)*4 + reg
#pragma unroll
    for (int mf = 0; mf < 4; ++mf)
#pragma unroll
      for (int q = 0; q < 4; ++q) {
        Sp[mf][q] += __builtin_amdgcn_exp2f(acc[mf][q]);
        acc[mf][q] = 0.0f;
      }
  }

  // reduce across the 16 columns (lanes sharing l4), then one atomic/row
#pragma unroll
  for (int mf = 0; mf < 4; ++mf)
#pragma unroll
    for (int q = 0; q < 4; ++q) {
      float v = Sp[mf][q];
      v += __shfl_xor(v, 1); v += __shfl_xor(v, 2);
      v += __shfl_xor(v, 4); v += __shfl_xor(v, 8);
      Sp[mf][q] = v;
    }
  if (l15 == 0) {
#pragma unroll
    for (int mf = 0; mf < 4; ++mf)
#pragma unroll
      for (int q = 0; q < 4; ++q)
        atomicAdd(&S[m0 + mf * 16 + l4 * 4 + q], Sp[mf][q]);
  }
}

// ---------------------------------------------------------------------------
// Kernel 3: loss = mean_i [ log(S_i - diagsub_i) - Pterm_i ]
// ---------------------------------------------------------------------------
__global__ __launch_bounds__(256) void finalize_kernel(
    const float* __restrict__ S, const float* __restrict__ Pterm,
    const float* __restrict__ diagsub, float* __restrict__ out)
{
  const int tid = threadIdx.x;
  float acc = 0.0f;
  for (int i = tid; i < NROWS; i += 256) {
    float v = S[i] - diagsub[i];
    acc += logf(fmaxf(v, 1e-20f)) - Pterm[i];
  }
#pragma unroll
  for (int m = 1; m < 64; m <<= 1) acc += __shfl_xor(acc, m);
  __shared__ float w[4];
  if ((tid & 63) == 0) w[tid >> 6] = acc;
  __syncthreads();
  if (tid == 0) out[0] = (w[0] + w[1] + w[2] + w[3]) * (1.0f / (float)NROWS);
}

// ---------------------------------------------------------------------------
extern "C" void kernel_launch(void* const* d_in, const int* in_sizes, int n_in,
                              void* d_out, int out_size, void* d_ws, size_t ws_size,
                              hipStream_t stream) {
  const float* h  = (const float*)d_in[0];
  const float* hg = (const float*)d_in[1];

  char* ws = (char*)d_ws;
  const size_t OFF_QS   = 0;                      // 4 MB
  const size_t OFF_KEYS = (size_t)4 << 20;        // 8 MB
  const size_t OFF_P    = (size_t)12 << 20;       // 32 KB
  const size_t OFF_DIAG = OFF_P + 32 * 1024;      // 32 KB
  const size_t OFF_S    = OFF_DIAG + 32 * 1024;   // 32 KB
  const size_t NEED     = OFF_S + 32 * 1024;
  if (ws_size < NEED) return;

  unsigned short* qs   = (unsigned short*)(ws + OFF_QS);
  unsigned short* keys = (unsigned short*)(ws + OFF_KEYS);
  float* Pterm   = (float*)(ws + OFF_P);
  float* diagsub = (float*)(ws + OFF_DIAG);
  float* S       = (float*)(ws + OFF_S);

  prep_kernel<<<NROWS, 64, 0, stream>>>(h, hg, qs, keys, Pterm, diagsub, S);
  nce_gemm<<<512, 512, 0, stream>>>(qs, keys, S);
  finalize_kernel<<<1, 256, 0, stream>>>(S, Pterm, diagsub, (float*)d_out);
}

// Round 5
// 107.423 us; speedup vs baseline: 5.7454x; 5.7454x over previous
//
#include <hip/hip_runtime.h>

// ---------- types ----------
typedef __attribute__((ext_vector_type(4))) float   float4_;
typedef __attribute__((ext_vector_type(4))) unsigned short ushort4_;
typedef __attribute__((ext_vector_type(8))) __bf16  bf16x8;
typedef __attribute__((ext_vector_type(4))) float   f32x4;

#define NROWS 8192
#define NKEYS 16384
#define DDIM  256

// exp(x/T) == exp2(x * C_SC)
static constexpr float T_INV = (float)(1.0 / 0.07);
static constexpr float C_SC  = (float)(1.0 / (0.07 * 0.6931471805599453));

__device__ __forceinline__ unsigned short f2bf(float x) {
  union { float f; unsigned int u; } v; v.f = x;
  unsigned int r = v.u + 0x7fffu + ((v.u >> 16) & 1u);   // RNE
  return (unsigned short)(r >> 16);
}
__device__ __forceinline__ float bf2f(unsigned short u) {
  union { unsigned int u; float f; } v; v.u = ((unsigned int)u) << 16; return v.f;
}

// ---------------------------------------------------------------------------
// Kernel 1: normalize rows, emit (ALL natural layouts); also zeroes S.
//   qs   [8192][256] bf16 : normalized q scaled by C_SC (MFMA A operand)
//   keys [16384][256] bf16: rows 0..8191 = q (unscaled), 8192.. = g (unscaled)
//   Pterm[row]   = dot(q,g)/T (fp32)
//   diagsub[row] = exp2(dot_fp32(qs_bf16, q_bf16))  — bf16-level qq diagonal
// ---------------------------------------------------------------------------
__global__ __launch_bounds__(64) void prep_kernel(
    const float* __restrict__ h, const float* __restrict__ g,
    unsigned short* __restrict__ qs, unsigned short* __restrict__ keys,
    float* __restrict__ Pterm, float* __restrict__ diagsub,
    float* __restrict__ S)
{
  const int row  = blockIdx.x;
  const int lane = threadIdx.x;            // 0..63, 4 dims each
  float4_ hv = *((const float4_*)h + row * 64 + lane);
  float4_ gv = *((const float4_*)g + row * 64 + lane);

  float ssh = hv.x*hv.x + hv.y*hv.y + hv.z*hv.z + hv.w*hv.w;
  float ssg = gv.x*gv.x + gv.y*gv.y + gv.z*gv.z + gv.w*gv.w;
#pragma unroll
  for (int m = 1; m < 64; m <<= 1) {
    ssh += __shfl_xor(ssh, m);
    ssg += __shfl_xor(ssg, m);
  }
  const float sh = 1.0f / fmaxf(sqrtf(ssh), 1e-8f);
  const float sg = 1.0f / fmaxf(sqrtf(ssg), 1e-8f);

  float qn[4] = { hv.x*sh, hv.y*sh, hv.z*sh, hv.w*sh };
  float gn[4] = { gv.x*sg, gv.y*sg, gv.z*sg, gv.w*sg };

  float pd = qn[0]*gn[0] + qn[1]*gn[1] + qn[2]*gn[2] + qn[3]*gn[3];

  unsigned short qb[4], qsb[4], gb[4];
  float dd = 0.0f;
#pragma unroll
  for (int j = 0; j < 4; ++j) {
    qb[j]  = f2bf(qn[j]);
    qsb[j] = f2bf(qn[j] * C_SC);
    gb[j]  = f2bf(gn[j]);
    dd += bf2f(qsb[j]) * bf2f(qb[j]);
  }
#pragma unroll
  for (int m = 1; m < 64; m <<= 1) {
    pd += __shfl_xor(pd, m);
    dd += __shfl_xor(dd, m);
  }

  ushort4_ vqs = { qsb[0], qsb[1], qsb[2], qsb[3] };
  ushort4_ vq  = { qb[0],  qb[1],  qb[2],  qb[3]  };
  ushort4_ vg  = { gb[0],  gb[1],  gb[2],  gb[3]  };
  *((ushort4_*)qs   + (size_t)row * 64 + lane)           = vqs;
  *((ushort4_*)keys + (size_t)row * 64 + lane)           = vq;
  *((ushort4_*)keys + (size_t)(NROWS + row) * 64 + lane) = vg;

  if (lane == 0) {
    Pterm[row]   = pd * T_INV;
    diagsub[row] = __builtin_amdgcn_exp2f(dd);
    S[row]       = 0.0f;                   // replaces the memset dispatch
  }
}

// ---------------------------------------------------------------------------
// Kernel 2: fused GEMM + exp2 + row-sum.
// Grid 512 = 64 M-tiles (BM=128) x 8 key-slices (2048 keys each).
// slice = bid & 7  -> each XCD owns one 1MB slice (L2-resident).
// 2 blocks/CU resident (64KB LDS) -> 16 waves/CU for phase overlap.
// 8 waves (2m x 4n); Q frags in registers (STATIC indices only — rule #20:
// runtime-indexed reg arrays demote to scratch; round 4 proved it at 8x cost).
// Keys reg-staged into double-buffered LDS, XOR swizzle applied at ds_write
// and undone at ds_read through the SAME lds_off().
// ---------------------------------------------------------------------------
__device__ __forceinline__ int lds_off(int r, int g) {   // elements
  return r * DDIM + (((g ^ (r & 7)) & 31) << 3);
}

__global__ __launch_bounds__(512, 2) void nce_gemm(
    const unsigned short* __restrict__ qs,
    const unsigned short* __restrict__ keys,
    float* __restrict__ S)
{
  __shared__ __align__(16) unsigned short lds_k[2 * 64 * DDIM]; // 64 KB

  const int tid  = threadIdx.x;
  const int wid  = tid >> 6;
  const int lane = tid & 63;
  const int l15  = lane & 15, l4 = lane >> 4;

  const int bid   = blockIdx.x;
  const int slice = bid & 7;               // == XCD id: slice L2-resident
  const int mtile = bid >> 3;              // 0..63

  const int wm = wid >> 2;                 // 0..1
  const int wn = wid & 3;                  // 0..3
  const int m0 = mtile * 128 + wm * 64;

  // ---- Q fragments into registers (natural layout, pre-scaled by C_SC) ----
  bf16x8 a[4][8];
#pragma unroll
  for (int mf = 0; mf < 4; ++mf) {
    const unsigned short* rp = qs + (size_t)(m0 + mf * 16 + l15) * DDIM + l4 * 8;
#pragma unroll
    for (int kk = 0; kk < 8; ++kk)
      a[mf][kk] = *(const bf16x8*)(rp + kk * 32);
  }

  const f32x4 zero4 = { 0.f, 0.f, 0.f, 0.f };
  f32x4 acc[4] = { zero4, zero4, zero4, zero4 };
  float Sp[4][4] = {};

  // staging map: thread t -> key-row sr = t>>3, groups (t&7)+8u, u=0..3
  const int sr  = tid >> 3;                // 0..63
  const int sg0 = tid & 7;
  const unsigned short* kslice = keys + (size_t)slice * 2048 * DDIM;

  bf16x8 stg[4];
  auto load_chunk = [&](int c) {
    const unsigned short* base = kslice + ((size_t)c * 64 + sr) * DDIM;
#pragma unroll
    for (int u = 0; u < 4; ++u)
      stg[u] = *(const bf16x8*)(base + ((sg0 + 8 * u) << 3));
  };
  auto write_chunk = [&](int buf) {
    unsigned short* dst = lds_k + buf * (64 * DDIM);
#pragma unroll
    for (int u = 0; u < 4; ++u)
      *(bf16x8*)(dst + lds_off(sr, sg0 + 8 * u)) = stg[u];
  };

  load_chunk(0);
  for (int c = 0; c < 32; ++c) {
    const int buf = c & 1;
    write_chunk(buf);
    __syncthreads();                       // LDS writes visible; dbuf-safe
    if (c + 1 < 32) load_chunk(c + 1);     // in flight across whole chunk

    const unsigned short* lb = lds_k + buf * (64 * DDIM);
#pragma unroll
    for (int kk = 0; kk < 8; ++kk) {       // STATIC index — stays in registers
      bf16x8 b = *(const bf16x8*)(lb + lds_off(wn * 16 + l15, kk * 4 + l4));
      __builtin_amdgcn_s_setprio(1);
#pragma unroll
      for (int mf = 0; mf < 4; ++mf)
        acc[mf] = __builtin_amdgcn_mfma_f32_16x16x32_bf16(a[mf][kk], b, acc[mf], 0, 0, 0);
      __builtin_amdgcn_s_setprio(0);
    }
    // harvest: D layout (m89): col = lane&15, row = (lane>>4)*4 + reg
#pragma unroll
    for (int mf = 0; mf < 4; ++mf)
#pragma unroll
      for (int q = 0; q < 4; ++q) {
        Sp[mf][q] += __builtin_amdgcn_exp2f(acc[mf][q]);
        acc[mf][q] = 0.0f;
      }
  }

  // reduce across the 16 columns (lanes sharing l4), then one atomic/row
#pragma unroll
  for (int mf = 0; mf < 4; ++mf)
#pragma unroll
    for (int q = 0; q < 4; ++q) {
      float v = Sp[mf][q];
      v += __shfl_xor(v, 1); v += __shfl_xor(v, 2);
      v += __shfl_xor(v, 4); v += __shfl_xor(v, 8);
      Sp[mf][q] = v;
    }
  if (l15 == 0) {
#pragma unroll
    for (int mf = 0; mf < 4; ++mf)
#pragma unroll
      for (int q = 0; q < 4; ++q)
        atomicAdd(&S[m0 + mf * 16 + l4 * 4 + q], Sp[mf][q]);
  }
}

// ---------------------------------------------------------------------------
// Kernel 3: loss = mean_i [ log(S_i - diagsub_i) - Pterm_i ]
// ---------------------------------------------------------------------------
__global__ __launch_bounds__(256) void finalize_kernel(
    const float* __restrict__ S, const float* __restrict__ Pterm,
    const float* __restrict__ diagsub, float* __restrict__ out)
{
  const int tid = threadIdx.x;
  float acc = 0.0f;
  for (int i = tid; i < NROWS; i += 256) {
    float v = S[i] - diagsub[i];
    acc += logf(fmaxf(v, 1e-20f)) - Pterm[i];
  }
#pragma unroll
  for (int m = 1; m < 64; m <<= 1) acc += __shfl_xor(acc, m);
  __shared__ float w[4];
  if ((tid & 63) == 0) w[tid >> 6] = acc;
  __syncthreads();
  if (tid == 0) out[0] = (w[0] + w[1] + w[2] + w[3]) * (1.0f / (float)NROWS);
}

// ---------------------------------------------------------------------------
extern "C" void kernel_launch(void* const* d_in, const int* in_sizes, int n_in,
                              void* d_out, int out_size, void* d_ws, size_t ws_size,
                              hipStream_t stream) {
  const float* h  = (const float*)d_in[0];
  const float* hg = (const float*)d_in[1];

  char* ws = (char*)d_ws;
  const size_t OFF_QS   = 0;                      // 4 MB
  const size_t OFF_KEYS = (size_t)4 << 20;        // 8 MB
  const size_t OFF_P    = (size_t)12 << 20;       // 32 KB
  const size_t OFF_DIAG = OFF_P + 32 * 1024;      // 32 KB
  const size_t OFF_S    = OFF_DIAG + 32 * 1024;   // 32 KB
  const size_t NEED     = OFF_S + 32 * 1024;
  if (ws_size < NEED) return;

  unsigned short* qs   = (unsigned short*)(ws + OFF_QS);
  unsigned short* keys = (unsigned short*)(ws + OFF_KEYS);
  float* Pterm   = (float*)(ws + OFF_P);
  float* diagsub = (float*)(ws + OFF_DIAG);
  float* S       = (float*)(ws + OFF_S);

  prep_kernel<<<NROWS, 64, 0, stream>>>(h, hg, qs, keys, Pterm, diagsub, S);
  nce_gemm<<<512, 512, 0, stream>>>(qs, keys, S);
  finalize_kernel<<<1, 256, 0, stream>>>(S, Pterm, diagsub, (float*)d_out);
}

// Round 6
// 92.604 us; speedup vs baseline: 6.6649x; 1.1600x over previous
//
#include <hip/hip_runtime.h>

// ---------- types ----------
typedef __attribute__((ext_vector_type(4))) float   float4_;
typedef __attribute__((ext_vector_type(4))) unsigned short ushort4_;
typedef __attribute__((ext_vector_type(8))) __bf16  bf16x8;
typedef __attribute__((ext_vector_type(4))) float   f32x4;

#define NROWS 8192
#define NKEYS 16384
#define DDIM  256

// exp(x/T) == exp2(x * C_SC)
static constexpr float T_INV = (float)(1.0 / 0.07);
static constexpr float C_SC  = (float)(1.0 / (0.07 * 0.6931471805599453));

__device__ __forceinline__ unsigned short f2bf(float x) {
  union { float f; unsigned int u; } v; v.f = x;
  unsigned int r = v.u + 0x7fffu + ((v.u >> 16) & 1u);   // RNE
  return (unsigned short)(r >> 16);
}
__device__ __forceinline__ float bf2f(unsigned short u) {
  union { unsigned int u; float f; } v; v.u = ((unsigned int)u) << 16; return v.f;
}

// ---------------------------------------------------------------------------
// Shared swizzle: byte offset of 16B-group g (0..31) of row r (0..63) inside
// one 32KB chunk image. Used by BOTH prep (global write) and gemm (ds_read):
// consistency by construction (rule #21 — both sides through one function).
// Bank math: bank = 4*((g ^ (r&7)) % 8) -> lanes with r&7 = 0..7 spread over
// all 32 banks for any fixed g.
// ---------------------------------------------------------------------------
__device__ __forceinline__ int swz_off(int r, int g) {
  return (r << 9) + (((g ^ (r & 7)) & 31) << 4);
}

// ---------------------------------------------------------------------------
// Kernel 1: normalize rows; emit qs (natural, scaled by C_SC) and keys in
// chunk-image layout: keys byte = (k>>6)*32768 + swz_off(k&63, g).
// Rows 0..8191 = q, 8192..16383 = g. Also Pterm, diagsub; zeroes S.
// ---------------------------------------------------------------------------
__global__ __launch_bounds__(64) void prep_kernel(
    const float* __restrict__ h, const float* __restrict__ g,
    unsigned short* __restrict__ qs, unsigned short* __restrict__ keys,
    float* __restrict__ Pterm, float* __restrict__ diagsub,
    float* __restrict__ S)
{
  const int row  = blockIdx.x;
  const int lane = threadIdx.x;            // 0..63, 4 dims each
  float4_ hv = *((const float4_*)h + row * 64 + lane);
  float4_ gv = *((const float4_*)g + row * 64 + lane);

  float ssh = hv.x*hv.x + hv.y*hv.y + hv.z*hv.z + hv.w*hv.w;
  float ssg = gv.x*gv.x + gv.y*gv.y + gv.z*gv.z + gv.w*gv.w;
#pragma unroll
  for (int m = 1; m < 64; m <<= 1) {
    ssh += __shfl_xor(ssh, m);
    ssg += __shfl_xor(ssg, m);
  }
  const float sh = 1.0f / fmaxf(sqrtf(ssh), 1e-8f);
  const float sg = 1.0f / fmaxf(sqrtf(ssg), 1e-8f);

  float qn[4] = { hv.x*sh, hv.y*sh, hv.z*sh, hv.w*sh };
  float gn[4] = { gv.x*sg, gv.y*sg, gv.z*sg, gv.w*sg };

  float pd = qn[0]*gn[0] + qn[1]*gn[1] + qn[2]*gn[2] + qn[3]*gn[3];

  unsigned short qb[4], qsb[4], gb[4];
  float dd = 0.0f;
#pragma unroll
  for (int j = 0; j < 4; ++j) {
    qb[j]  = f2bf(qn[j]);
    qsb[j] = f2bf(qn[j] * C_SC);
    gb[j]  = f2bf(gn[j]);
    dd += bf2f(qsb[j]) * bf2f(qb[j]);
  }
#pragma unroll
  for (int m = 1; m < 64; m <<= 1) {
    pd += __shfl_xor(pd, m);
    dd += __shfl_xor(dd, m);
  }

  ushort4_ vqs = { qsb[0], qsb[1], qsb[2], qsb[3] };
  ushort4_ vq  = { qb[0],  qb[1],  qb[2],  qb[3]  };
  ushort4_ vg  = { gb[0],  gb[1],  gb[2],  gb[3]  };
  *((ushort4_*)qs + (size_t)row * 64 + lane) = vqs;   // natural layout

  // keys in chunk-image layout (8B half of 16B group g = lane>>1)
  const int grp  = lane >> 1;
  const int half = (lane & 1) << 3;
  char* kb = (char*)keys;
  {
    const int k = row;
    *(ushort4_*)(kb + (((size_t)(k >> 6)) << 15) + swz_off(k & 63, grp) + half) = vq;
  }
  {
    const int k = NROWS + row;
    *(ushort4_*)(kb + (((size_t)(k >> 6)) << 15) + swz_off(k & 63, grp) + half) = vg;
  }

  if (lane == 0) {
    Pterm[row]   = pd * T_INV;
    diagsub[row] = __builtin_amdgcn_exp2f(dd);
    S[row]       = 0.0f;                   // replaces the memset dispatch
  }
}

// ---------------------------------------------------------------------------
// Kernel 2: fused GEMM + exp2 + row-sum.
// Grid 256 = 64 M-tiles (BM=128) x 4 key-slices (4096 keys, 64 chunks of 64).
// slice = bid & 3; one 8-wave block per CU (regs cap occupancy at 8 waves/CU
// — measured r3/r5; the 128 A-frag regs buy LDS-amp=2, keep them).
// Staging: global_load_lds width=16, linear dest; source pre-swizzled by
// prep's swz_off -> ds_read through the SAME swz_off is conflict-spread.
// One barrier per chunk; loads for c+1 issued right after barrier c (in
// flight across the whole MFMA phase; barrier's vmcnt(0) drain is cheap).
// ---------------------------------------------------------------------------
typedef __attribute__((address_space(1))) const unsigned int gu32;
typedef __attribute__((address_space(3))) unsigned int       lu32;

__global__ __launch_bounds__(512, 2) void nce_gemm(
    const unsigned short* __restrict__ qs,
    const unsigned short* __restrict__ keys,
    float* __restrict__ S)
{
  __shared__ __align__(16) char lds_k[2 * 32768];    // 64 KB double buffer

  const int tid  = threadIdx.x;
  const int wid  = tid >> 6;
  const int lane = tid & 63;
  const int l15  = lane & 15, l4 = lane >> 4;

  const int bid   = blockIdx.x;
  const int slice = bid & 3;               // constant per XCD
  const int mtile = bid >> 2;              // 0..63

  const int wm = wid >> 2;                 // 0..1
  const int wn = wid & 3;                  // 0..3
  const int m0 = mtile * 128 + wm * 64;

  // ---- Q fragments into registers (natural layout, pre-scaled by C_SC) ----
  bf16x8 a[4][8];
#pragma unroll
  for (int mf = 0; mf < 4; ++mf) {
    const unsigned short* rp = qs + (size_t)(m0 + mf * 16 + l15) * DDIM + l4 * 8;
#pragma unroll
    for (int kk = 0; kk < 8; ++kk)
      a[mf][kk] = *(const bf16x8*)(rp + kk * 32);
  }

  // per-chunk loop-invariant ds_read byte offsets (static-index array)
  const int rr = wn * 16 + l15;            // key row within chunk 0..63
  int boff[8];
#pragma unroll
  for (int kk = 0; kk < 8; ++kk)
    boff[kk] = swz_off(rr, kk * 4 + l4);

  const f32x4 zero4 = { 0.f, 0.f, 0.f, 0.f };
  f32x4 acc[4] = { zero4, zero4, zero4, zero4 };
  float Sp[4][4] = {};

  const char* kbytes = (const char*)keys;

  // stage chunk c (32KB image) into LDS buffer c&1: linear byte copy.
  // dst is wave-uniform base (HW adds lane*16); src is per-lane.
  auto stage = [&](int c) {
    const char* src = kbytes + (((size_t)(slice * 64 + c)) << 15);
    char* dst = lds_k + (c & 1) * 32768;
#pragma unroll
    for (int i = 0; i < 4; ++i) {
      const int sub = (i << 3) + wid;      // 1KB sub-chunk 0..31
      __builtin_amdgcn_global_load_lds(
          (gu32*)(src + (sub << 10) + (lane << 4)),
          (lu32*)(dst + (sub << 10)),
          16, 0, 0);
    }
  };

  stage(0);
  for (int c = 0; c < 64; ++c) {
    __syncthreads();                       // vmcnt drain: chunk c landed;
                                           // also fences reads of buf (c-1)
    if (c + 1 < 64) stage(c + 1);          // async into the other buffer

    const char* lb = lds_k + (c & 1) * 32768;
    bf16x8 b[8];
#pragma unroll
    for (int kk = 0; kk < 8; ++kk)         // issue reads first...
      b[kk] = *(const bf16x8*)(lb + boff[kk]);

    if (c > 0) {                           // ...harvest prev under LDS latency
#pragma unroll
      for (int mf = 0; mf < 4; ++mf)
#pragma unroll
        for (int q = 0; q < 4; ++q)
          Sp[mf][q] += __builtin_amdgcn_exp2f(acc[mf][q]);
    }

#pragma unroll
    for (int kk = 0; kk < 8; ++kk) {
#pragma unroll
      for (int mf = 0; mf < 4; ++mf)
        acc[mf] = __builtin_amdgcn_mfma_f32_16x16x32_bf16(
            a[mf][kk], b[kk], kk == 0 ? zero4 : acc[mf], 0, 0, 0);
    }
  }
#pragma unroll
  for (int mf = 0; mf < 4; ++mf)           // last chunk's harvest
#pragma unroll
    for (int q = 0; q < 4; ++q)
      Sp[mf][q] += __builtin_amdgcn_exp2f(acc[mf][q]);

  // reduce across the 16 columns (lanes sharing l4), then one atomic/row
#pragma unroll
  for (int mf = 0; mf < 4; ++mf)
#pragma unroll
    for (int q = 0; q < 4; ++q) {
      float v = Sp[mf][q];
      v += __shfl_xor(v, 1); v += __shfl_xor(v, 2);
      v += __shfl_xor(v, 4); v += __shfl_xor(v, 8);
      Sp[mf][q] = v;
    }
  if (l15 == 0) {
#pragma unroll
    for (int mf = 0; mf < 4; ++mf)
#pragma unroll
      for (int q = 0; q < 4; ++q)
        atomicAdd(&S[m0 + mf * 16 + l4 * 4 + q], Sp[mf][q]);
  }
}

// ---------------------------------------------------------------------------
// Kernel 3: loss = mean_i [ log(S_i - diagsub_i) - Pterm_i ]
// ---------------------------------------------------------------------------
__global__ __launch_bounds__(256) void finalize_kernel(
    const float* __restrict__ S, const float* __restrict__ Pterm,
    const float* __restrict__ diagsub, float* __restrict__ out)
{
  const int tid = threadIdx.x;
  float acc = 0.0f;
  for (int i = tid; i < NROWS; i += 256) {
    float v = S[i] - diagsub[i];
    acc += logf(fmaxf(v, 1e-20f)) - Pterm[i];
  }
#pragma unroll
  for (int m = 1; m < 64; m <<= 1) acc += __shfl_xor(acc, m);
  __shared__ float w[4];
  if ((tid & 63) == 0) w[tid >> 6] = acc;
  __syncthreads();
  if (tid == 0) out[0] = (w[0] + w[1] + w[2] + w[3]) * (1.0f / (float)NROWS);
}

// ---------------------------------------------------------------------------
extern "C" void kernel_launch(void* const* d_in, const int* in_sizes, int n_in,
                              void* d_out, int out_size, void* d_ws, size_t ws_size,
                              hipStream_t stream) {
  const float* h  = (const float*)d_in[0];
  const float* hg = (const float*)d_in[1];

  char* ws = (char*)d_ws;
  const size_t OFF_QS   = 0;                      // 4 MB
  const size_t OFF_KEYS = (size_t)4 << 20;        // 8 MB
  const size_t OFF_P    = (size_t)12 << 20;       // 32 KB
  const size_t OFF_DIAG = OFF_P + 32 * 1024;      // 32 KB
  const size_t OFF_S    = OFF_DIAG + 32 * 1024;   // 32 KB
  const size_t NEED     = OFF_S + 32 * 1024;
  if (ws_size < NEED) return;

  unsigned short* qs   = (unsigned short*)(ws + OFF_QS);
  unsigned short* keys = (unsigned short*)(ws + OFF_KEYS);
  float* Pterm   = (float*)(ws + OFF_P);
  float* diagsub = (float*)(ws + OFF_DIAG);
  float* S       = (float*)(ws + OFF_S);

  prep_kernel<<<NROWS, 64, 0, stream>>>(h, hg, qs, keys, Pterm, diagsub, S);
  nce_gemm<<<256, 512, 0, stream>>>(qs, keys, S);
  finalize_kernel<<<1, 256, 0, stream>>>(S, Pterm, diagsub, (float*)d_out);
}

// Round 7
// 74.387 us; speedup vs baseline: 8.2970x; 1.2449x over previous
//
#include <hip/hip_runtime.h>

// ---------- types ----------
typedef __attribute__((ext_vector_type(4))) float float4_;
typedef __attribute__((ext_vector_type(4))) float f32x4;

#define NROWS 8192
#define NKEYS 16384
#define DDIM  256

// exp(x/T) == exp2(x * C_SC)
static constexpr float T_INV = (float)(1.0 / 0.07);
static constexpr float C_SC  = (float)(1.0 / (0.07 * 0.6931471805599453));

// ---------------------------------------------------------------------------
// fp8 chunk-image swizzle: byte offset of 8B-group g (0..31) of row r
// (0..255) inside one 64KB chunk image (256 keys x 256 fp8 bytes).
// Used by BOTH prep (global write) and gemm (ds_read after a LINEAR
// global_load_lds copy) — rule #21: one function, both sides.
// Bank math (ds_read_b64): group g' = g ^ (r&31); 16 lanes sharing l4 have
// 16 consecutive (r&31) values -> 16 distinct g' mod 16 -> 16 distinct
// 2-bank pairs = 32 banks; 4 l4-groups alias 4-deep = the wave64-b64
// structural minimum (512B/128B = 4 cy). Conflict-free.
// ---------------------------------------------------------------------------
__device__ __forceinline__ int swz8(int r, int g) {
  return (r << 8) + (((g ^ (r & 31)) & 31) << 3);
}

// ---------------------------------------------------------------------------
// Kernel 1: normalize rows; emit fp8 e4m3 (OCP, HW cvt):
//   qs8  [8192][256] fp8: normalized q scaled by C_SC (MFMA A), natural.
//   keys8: 64 chunk images of 64KB: key k -> image (k>>8), row k&255,
//          byte = swz8(r, d>>3) + (d&7). Keys 0..8191 = q, 8192.. = g.
//   Pterm[row] = dot_f32(q,g)/T ; diagsub[row] = exp2(dot_f32 of the
//   fp8-ROUNDED qs8[i]·q8[i]) — exact qq-diagonal cancellation.
// Also zeroes S.
// ---------------------------------------------------------------------------
__global__ __launch_bounds__(256) void prep_kernel(
    const float* __restrict__ h, const float* __restrict__ g,
    unsigned int* __restrict__ qs8, unsigned int* __restrict__ keys8,
    float* __restrict__ Pterm, float* __restrict__ diagsub,
    float* __restrict__ S)
{
  const int row  = blockIdx.x * 4 + (threadIdx.x >> 6);
  const int lane = threadIdx.x & 63;       // 4 dims each
  float4_ hv = *((const float4_*)h + row * 64 + lane);
  float4_ gv = *((const float4_*)g + row * 64 + lane);

  float ssh = hv.x*hv.x + hv.y*hv.y + hv.z*hv.z + hv.w*hv.w;
  float ssg = gv.x*gv.x + gv.y*gv.y + gv.z*gv.z + gv.w*gv.w;
#pragma unroll
  for (int m = 1; m < 64; m <<= 1) {
    ssh += __shfl_xor(ssh, m);
    ssg += __shfl_xor(ssg, m);
  }
  const float sh = 1.0f / fmaxf(sqrtf(ssh), 1e-8f);
  const float sg = 1.0f / fmaxf(sqrtf(ssg), 1e-8f);

  float qn[4] = { hv.x*sh, hv.y*sh, hv.z*sh, hv.w*sh };
  float gn[4] = { gv.x*sg, gv.y*sg, gv.z*sg, gv.w*sg };

  float pd = qn[0]*gn[0] + qn[1]*gn[1] + qn[2]*gn[2] + qn[3]*gn[3];

  // fp8 packs (RNE, saturating). word_sel / byte_sel must be literals.
  int pq = __builtin_amdgcn_cvt_pk_fp8_f32(qn[0], qn[1], 0, 0);
  pq     = __builtin_amdgcn_cvt_pk_fp8_f32(qn[2], qn[3], pq, 1);
  int ps = __builtin_amdgcn_cvt_pk_fp8_f32(qn[0]*C_SC, qn[1]*C_SC, 0, 0);
  ps     = __builtin_amdgcn_cvt_pk_fp8_f32(qn[2]*C_SC, qn[3]*C_SC, ps, 1);
  int pg = __builtin_amdgcn_cvt_pk_fp8_f32(gn[0], gn[1], 0, 0);
  pg     = __builtin_amdgcn_cvt_pk_fp8_f32(gn[2], gn[3], pg, 1);

  float dd =
      __builtin_amdgcn_cvt_f32_fp8(ps, 0) * __builtin_amdgcn_cvt_f32_fp8(pq, 0)
    + __builtin_amdgcn_cvt_f32_fp8(ps, 1) * __builtin_amdgcn_cvt_f32_fp8(pq, 1)
    + __builtin_amdgcn_cvt_f32_fp8(ps, 2) * __builtin_amdgcn_cvt_f32_fp8(pq, 2)
    + __builtin_amdgcn_cvt_f32_fp8(ps, 3) * __builtin_amdgcn_cvt_f32_fp8(pq, 3);

#pragma unroll
  for (int m = 1; m < 64; m <<= 1) {
    pd += __shfl_xor(pd, m);
    dd += __shfl_xor(dd, m);
  }

  qs8[(size_t)row * 64 + lane] = (unsigned int)ps;   // natural, coalesced

  char* kb = (char*)keys8;
  const int grp  = lane >> 1;              // 8B group 0..31
  const int half = (lane & 1) << 2;        // 4B half within group
  {
    const int k = row;
    *(unsigned int*)(kb + (((size_t)(k >> 8)) << 16)
                     + swz8(k & 255, grp) + half) = (unsigned int)pq;
  }
  {
    const int k = NROWS + row;
    *(unsigned int*)(kb + (((size_t)(k >> 8)) << 16)
                     + swz8(k & 255, grp) + half) = (unsigned int)pg;
  }

  if (lane == 0) {
    Pterm[row]   = pd * T_INV;
    diagsub[row] = __builtin_amdgcn_exp2f(dd);
    S[row]       = 0.0f;
  }
}

// ---------------------------------------------------------------------------
// Kernel 2: fused fp8 GEMM + exp2 + row-sum.
// Grid 256 = 64 M-tiles (BM=128) x 4 key-slices (4096 keys = 16 chunks of
// 256). slice = bid & 3 (XCD-resident). 8 waves (2m x 4n); A-frags in regs
// (static idx only — rule #20); keys: global_load_lds width-16 LINEAR copy
// of prep's pre-swizzled 64KB images into a 128KB LDS double buffer.
// 16 iterations: 4x MFMA per barrier vs r6 — amortizes the lockstep serial
// phase that pinned MfmaUtil at the 36% m97-structure ceiling.
// ---------------------------------------------------------------------------
typedef __attribute__((address_space(1))) const unsigned int gu32;
typedef __attribute__((address_space(3))) unsigned int       lu32;

__global__ __launch_bounds__(512, 1) void nce_gemm(
    const unsigned int* __restrict__ qs8,
    const unsigned int* __restrict__ keys8,
    float* __restrict__ S)
{
  __shared__ __align__(16) char lds_k[2 * 65536];    // 128 KB double buffer

  const int tid  = threadIdx.x;
  const int wid  = tid >> 6;
  const int lane = tid & 63;
  const int l15  = lane & 15, l4 = lane >> 4;

  const int bid   = blockIdx.x;
  const int slice = bid & 3;               // constant per XCD
  const int mtile = bid >> 2;              // 0..63

  const int wm = wid >> 2;                 // 0..1
  const int wn = wid & 3;                  // 0..3
  const int m0 = mtile * 128 + wm * 64;

  // ---- A fragments: 8B of K per (mf, kk); K elem = kk*32 + l4*8 + j ----
  const char* qb = (const char*)qs8;
  long a8[4][8];
#pragma unroll
  for (int mf = 0; mf < 4; ++mf) {
    const char* rp = qb + (size_t)(m0 + mf * 16 + l15) * 256 + l4 * 8;
#pragma unroll
    for (int kk = 0; kk < 8; ++kk)
      a8[mf][kk] = *(const long*)(rp + kk * 32);
  }

  // per-chunk loop-invariant ds_read offsets for colt==0 (colt adds 16384)
  const int rr0 = wn * 16 + l15;           // key row within chunk, colt 0
  int boff0[8];
#pragma unroll
  for (int kk = 0; kk < 8; ++kk)
    boff0[kk] = swz8(rr0, kk * 4 + l4);

  const f32x4 zero4 = { 0.f, 0.f, 0.f, 0.f };
  f32x4 acc[4][4];                         // [colt][mf]
  float Sp[4][4] = {};                     // [mf][q] row-sums

  const char* kbytes = (const char*)keys8;

  // stage chunk c (64KB image) linearly into LDS buffer c&1
  auto stage = [&](int c) {
    const char* src = kbytes + (((size_t)(slice * 16 + c)) << 16);
    char* dst = lds_k + (c & 1) * 65536;
#pragma unroll
    for (int i = 0; i < 8; ++i) {
      const int sub = (i << 3) + wid;      // 1KB sub-chunk 0..63
      __builtin_amdgcn_global_load_lds(
          (gu32*)(src + (sub << 10) + (lane << 4)),
          (lu32*)(dst + (sub << 10)),
          16, 0, 0);
    }
  };

  stage(0);
  for (int c = 0; c < 16; ++c) {
    __syncthreads();                       // chunk c landed; buf (c-1) free
    if (c + 1 < 16) stage(c + 1);          // async across whole chunk

    const char* lb = lds_k + (c & 1) * 65536;
#pragma unroll
    for (int colt = 0; colt < 4; ++colt) {
      long b8[8];
#pragma unroll
      for (int kk = 0; kk < 8; ++kk)
        b8[kk] = *(const long*)(lb + boff0[kk] + colt * 16384);

      if (colt == 0 && c > 0) {            // harvest prev chunk under latency
#pragma unroll
        for (int ct = 0; ct < 4; ++ct)
#pragma unroll
          for (int mf = 0; mf < 4; ++mf)
#pragma unroll
            for (int q = 0; q < 4; ++q)
              Sp[mf][q] += __builtin_amdgcn_exp2f(acc[ct][mf][q]);
      }

#pragma unroll
      for (int kk = 0; kk < 8; ++kk)
#pragma unroll
        for (int mf = 0; mf < 4; ++mf)
          acc[colt][mf] = __builtin_amdgcn_mfma_f32_16x16x32_fp8_fp8(
              a8[mf][kk], b8[kk], kk == 0 ? zero4 : acc[colt][mf], 0, 0, 0);
    }
  }
#pragma unroll
  for (int ct = 0; ct < 4; ++ct)           // last chunk's harvest
#pragma unroll
    for (int mf = 0; mf < 4; ++mf)
#pragma unroll
      for (int q = 0; q < 4; ++q)
        Sp[mf][q] += __builtin_amdgcn_exp2f(acc[ct][mf][q]);

  // reduce across the 16 columns (lanes sharing l4), then one atomic/row
#pragma unroll
  for (int mf = 0; mf < 4; ++mf)
#pragma unroll
    for (int q = 0; q < 4; ++q) {
      float v = Sp[mf][q];
      v += __shfl_xor(v, 1); v += __shfl_xor(v, 2);
      v += __shfl_xor(v, 4); v += __shfl_xor(v, 8);
      Sp[mf][q] = v;
    }
  if (l15 == 0) {
#pragma unroll
    for (int mf = 0; mf < 4; ++mf)
#pragma unroll
      for (int q = 0; q < 4; ++q)
        atomicAdd(&S[m0 + mf * 16 + l4 * 4 + q], Sp[mf][q]);
  }
}

// ---------------------------------------------------------------------------
// Kernel 3: loss = mean_i [ log(S_i - diagsub_i) - Pterm_i ]
// ---------------------------------------------------------------------------
__global__ __launch_bounds__(256) void finalize_kernel(
    const float* __restrict__ S, const float* __restrict__ Pterm,
    const float* __restrict__ diagsub, float* __restrict__ out)
{
  const int tid = threadIdx.x;
  float acc = 0.0f;
  for (int i = tid; i < NROWS; i += 256) {
    float v = S[i] - diagsub[i];
    acc += logf(fmaxf(v, 1e-20f)) - Pterm[i];
  }
#pragma unroll
  for (int m = 1; m < 64; m <<= 1) acc += __shfl_xor(acc, m);
  __shared__ float w[4];
  if ((tid & 63) == 0) w[tid >> 6] = acc;
  __syncthreads();
  if (tid == 0) out[0] = (w[0] + w[1] + w[2] + w[3]) * (1.0f / (float)NROWS);
}

// ---------------------------------------------------------------------------
extern "C" void kernel_launch(void* const* d_in, const int* in_sizes, int n_in,
                              void* d_out, int out_size, void* d_ws, size_t ws_size,
                              hipStream_t stream) {
  const float* h  = (const float*)d_in[0];
  const float* hg = (const float*)d_in[1];

  char* ws = (char*)d_ws;
  const size_t OFF_QS   = 0;                      // 2 MB (8192*256 fp8)
  const size_t OFF_KEYS = (size_t)2 << 20;        // 4 MB (16384*256 fp8)
  const size_t OFF_P    = (size_t)6 << 20;        // 32 KB
  const size_t OFF_DIAG = OFF_P + 32 * 1024;      // 32 KB
  const size_t OFF_S    = OFF_DIAG + 32 * 1024;   // 32 KB
  const size_t NEED     = OFF_S + 32 * 1024;
  if (ws_size < NEED) return;

  unsigned int* qs8   = (unsigned int*)(ws + OFF_QS);
  unsigned int* keys8 = (unsigned int*)(ws + OFF_KEYS);
  float* Pterm   = (float*)(ws + OFF_P);
  float* diagsub = (float*)(ws + OFF_DIAG);
  float* S       = (float*)(ws + OFF_S);

  prep_kernel<<<2048, 256, 0, stream>>>(h, hg, qs8, keys8, Pterm, diagsub, S);
  nce_gemm<<<256, 512, 0, stream>>>(qs8, keys8, S);
  finalize_kernel<<<1, 256, 0, stream>>>(S, Pterm, diagsub, (float*)d_out);
}

// Round 8
// 64.117 us; speedup vs baseline: 9.6260x; 1.1602x over previous
//
#include <hip/hip_runtime.h>

// ---------- types ----------
typedef __attribute__((ext_vector_type(4))) float float4_;
typedef __attribute__((ext_vector_type(4))) float f32x4;
typedef __attribute__((ext_vector_type(8))) int   i32x8;

#define NROWS 8192
#define NKEYS 16384
#define DDIM  256

// exp(x/T) == exp2(x * C_SC)
static constexpr float T_INV = (float)(1.0 / 0.07);
static constexpr float C_SC  = (float)(1.0 / (0.07 * 0.6931471805599453));

// ---------------------------------------------------------------------------
// fp8 chunk-image swizzle, 32B granularity: byte offset of 32B-group g32
// (0..7) of row r (0..255) inside one 64KB chunk image (256 keys x 256 B).
// Used by BOTH prep (global write) and gemm (ds_read after LINEAR
// global_load_lds copy) — rule #21: one function, both sides.
// Bank math (2x ds_read_b128 per 32B): 16 lanes sharing l4 have r = base+l15
// -> r&7 covers 0..7 twice -> g32' = g32^(r&7) hits all 8 distinct 32B slots
// twice -> 32 banks, 2 lanes/bank = free (m136).
// ---------------------------------------------------------------------------
__device__ __forceinline__ int swz32(int r, int g32) {
  return (r << 8) + (((g32 ^ (r & 7)) & 7) << 5);
}

// ---------------------------------------------------------------------------
// Kernel 1: normalize rows; emit fp8 e4m3 (OCP, HW cvt):
//   qs8  [8192][256] fp8: normalized q scaled by C_SC (MFMA A), natural.
//   keys8: 64 chunk images of 64KB: key k -> image (k>>8), row k&255,
//          dword at swz32(r, d>>5) + (d&31). Keys 0..8191 = q, 8192.. = g.
//   Pterm[row] = dot_f32(q,g)/T ; diagsub[row] = exp2(dot_f32 of the
//   fp8-ROUNDED qs8[i]·q8[i]) — exact qq-diagonal cancellation.
// Also zeroes S.
// ---------------------------------------------------------------------------
__global__ __launch_bounds__(256) void prep_kernel(
    const float* __restrict__ h, const float* __restrict__ g,
    unsigned int* __restrict__ qs8, unsigned int* __restrict__ keys8,
    float* __restrict__ Pterm, float* __restrict__ diagsub,
    float* __restrict__ S)
{
  const int row  = blockIdx.x * 4 + (threadIdx.x >> 6);
  const int lane = threadIdx.x & 63;       // 4 dims each
  float4_ hv = *((const float4_*)h + row * 64 + lane);
  float4_ gv = *((const float4_*)g + row * 64 + lane);

  float ssh = hv.x*hv.x + hv.y*hv.y + hv.z*hv.z + hv.w*hv.w;
  float ssg = gv.x*gv.x + gv.y*gv.y + gv.z*gv.z + gv.w*gv.w;
#pragma unroll
  for (int m = 1; m < 64; m <<= 1) {
    ssh += __shfl_xor(ssh, m);
    ssg += __shfl_xor(ssg, m);
  }
  const float sh = 1.0f / fmaxf(sqrtf(ssh), 1e-8f);
  const float sg = 1.0f / fmaxf(sqrtf(ssg), 1e-8f);

  float qn[4] = { hv.x*sh, hv.y*sh, hv.z*sh, hv.w*sh };
  float gn[4] = { gv.x*sg, gv.y*sg, gv.z*sg, gv.w*sg };

  float pd = qn[0]*gn[0] + qn[1]*gn[1] + qn[2]*gn[2] + qn[3]*gn[3];

  // fp8 packs (RNE, saturating). word_sel / byte_sel must be literals.
  int pq = __builtin_amdgcn_cvt_pk_fp8_f32(qn[0], qn[1], 0, 0);
  pq     = __builtin_amdgcn_cvt_pk_fp8_f32(qn[2], qn[3], pq, 1);
  int ps = __builtin_amdgcn_cvt_pk_fp8_f32(qn[0]*C_SC, qn[1]*C_SC, 0, 0);
  ps     = __builtin_amdgcn_cvt_pk_fp8_f32(qn[2]*C_SC, qn[3]*C_SC, ps, 1);
  int pg = __builtin_amdgcn_cvt_pk_fp8_f32(gn[0], gn[1], 0, 0);
  pg     = __builtin_amdgcn_cvt_pk_fp8_f32(gn[2], gn[3], pg, 1);

  float dd =
      __builtin_amdgcn_cvt_f32_fp8(ps, 0) * __builtin_amdgcn_cvt_f32_fp8(pq, 0)
    + __builtin_amdgcn_cvt_f32_fp8(ps, 1) * __builtin_amdgcn_cvt_f32_fp8(pq, 1)
    + __builtin_amdgcn_cvt_f32_fp8(ps, 2) * __builtin_amdgcn_cvt_f32_fp8(pq, 2)
    + __builtin_amdgcn_cvt_f32_fp8(ps, 3) * __builtin_amdgcn_cvt_f32_fp8(pq, 3);

#pragma unroll
  for (int m = 1; m < 64; m <<= 1) {
    pd += __shfl_xor(pd, m);
    dd += __shfl_xor(dd, m);
  }

  qs8[(size_t)row * 64 + lane] = (unsigned int)ps;   // natural, coalesced

  char* kb = (char*)keys8;
  const int g32 = lane >> 3;               // 32B group 0..7
  const int sub = (lane & 7) << 2;         // dword within group
  {
    const int k = row;
    *(unsigned int*)(kb + (((size_t)(k >> 8)) << 16)
                     + swz32(k & 255, g32) + sub) = (unsigned int)pq;
  }
  {
    const int k = NROWS + row;
    *(unsigned int*)(kb + (((size_t)(k >> 8)) << 16)
                     + swz32(k & 255, g32) + sub) = (unsigned int)pg;
  }

  if (lane == 0) {
    Pterm[row]   = pd * T_INV;
    diagsub[row] = __builtin_amdgcn_exp2f(dd);
    S[row]       = 0.0f;
  }
}

// ---------------------------------------------------------------------------
// Kernel 2: fused MX-fp8 GEMM (K=128/instr, scale=1.0) + exp2 + row-sum.
// Grid 256 = 64 M-tiles (BM=128) x 4 key-slices (4096 keys = 16 chunks of
// 256). slice = bid & 3 (XCD-resident). 8 waves (2m x 4n); A-frags in regs
// (static idx only — rule #20); keys: global_load_lds width-16 LINEAR copy
// of prep's pre-swizzled 64KB images into a 128KB LDS double buffer.
// vs r7: mfma_scale_f32_16x16x128_f8f6f4 -> 4x fewer MFMA instructions at
// ~2.3x FLOP rate (4661 vs 2047 TF ubench); C/D layout unchanged (shape-
// determined, m121-m128), so harvest/reduce path is r7's verified code.
// ---------------------------------------------------------------------------
typedef __attribute__((address_space(1))) const unsigned int gu32;
typedef __attribute__((address_space(3))) unsigned int       lu32;

__global__ __launch_bounds__(512, 1) void nce_gemm(
    const unsigned int* __restrict__ qs8,
    const unsigned int* __restrict__ keys8,
    float* __restrict__ S)
{
  __shared__ __align__(16) char lds_k[2 * 65536];    // 128 KB double buffer

  const int tid  = threadIdx.x;
  const int wid  = tid >> 6;
  const int lane = tid & 63;
  const int l15  = lane & 15, l4 = lane >> 4;

  const int bid   = blockIdx.x;
  const int slice = bid & 3;               // constant per XCD
  const int mtile = bid >> 2;              // 0..63

  const int wm = wid >> 2;                 // 0..1
  const int wn = wid & 3;                  // 0..3
  const int m0 = mtile * 128 + wm * 64;

  // ---- A fragments: 32B of K per (mf, kk); K elem = kk*128 + l4*32 + j ----
  const char* qb = (const char*)qs8;
  i32x8 a8[4][2];
#pragma unroll
  for (int mf = 0; mf < 4; ++mf) {
    const char* rp = qb + (size_t)(m0 + mf * 16 + l15) * 256 + l4 * 32;
#pragma unroll
    for (int kk = 0; kk < 2; ++kk)
      a8[mf][kk] = *(const i32x8*)(rp + kk * 128);
  }

  // per-chunk loop-invariant ds_read offsets for colt==0 (colt adds 16384)
  const int rr0 = wn * 16 + l15;           // key row within chunk, colt 0
  int boff0[2];
#pragma unroll
  for (int kk = 0; kk < 2; ++kk)
    boff0[kk] = swz32(rr0, kk * 4 + l4);

  const f32x4 zero4 = { 0.f, 0.f, 0.f, 0.f };
  f32x4 acc[4][4];                         // [colt][mf]
  float Sp[4][4] = {};                     // [mf][q] row-sums

  const char* kbytes = (const char*)keys8;

  // stage chunk c (64KB image) linearly into LDS buffer c&1
  auto stage = [&](int c) {
    const char* src = kbytes + (((size_t)(slice * 16 + c)) << 16);
    char* dst = lds_k + (c & 1) * 65536;
#pragma unroll
    for (int i = 0; i < 8; ++i) {
      const int sub = (i << 3) + wid;      // 1KB sub-chunk 0..63
      __builtin_amdgcn_global_load_lds(
          (gu32*)(src + (sub << 10) + (lane << 4)),
          (lu32*)(dst + (sub << 10)),
          16, 0, 0);
    }
  };

  stage(0);
  for (int c = 0; c < 16; ++c) {
    __syncthreads();                       // chunk c landed; buf (c-1) free
    if (c + 1 < 16) stage(c + 1);          // async across whole chunk

    const char* lb = lds_k + (c & 1) * 65536;
#pragma unroll
    for (int colt = 0; colt < 4; ++colt) {
      i32x8 b8[2];
#pragma unroll
      for (int kk = 0; kk < 2; ++kk)
        b8[kk] = *(const i32x8*)(lb + boff0[kk] + colt * 16384);

      if (colt == 0 && c > 0) {            // harvest prev chunk under latency
#pragma unroll
        for (int ct = 0; ct < 4; ++ct)
#pragma unroll
          for (int mf = 0; mf < 4; ++mf)
#pragma unroll
            for (int q = 0; q < 4; ++q)
              Sp[mf][q] += __builtin_amdgcn_exp2f(acc[ct][mf][q]);
      }

      // cbsz=0 (A fmt fp8 e4m3), blgp=0 (B fmt fp8), scales 127 = x1.0
#pragma unroll
      for (int kk = 0; kk < 2; ++kk)
#pragma unroll
        for (int mf = 0; mf < 4; ++mf)
          acc[colt][mf] = __builtin_amdgcn_mfma_scale_f32_16x16x128_f8f6f4(
              a8[mf][kk], b8[kk], kk == 0 ? zero4 : acc[colt][mf],
              0, 0, 0, 127, 0, 127);
    }
  }
#pragma unroll
  for (int ct = 0; ct < 4; ++ct)           // last chunk's harvest
#pragma unroll
    for (int mf = 0; mf < 4; ++mf)
#pragma unroll
      for (int q = 0; q < 4; ++q)
        Sp[mf][q] += __builtin_amdgcn_exp2f(acc[ct][mf][q]);

  // reduce across the 16 columns (lanes sharing l4), then one atomic/row
#pragma unroll
  for (int mf = 0; mf < 4; ++mf)
#pragma unroll
    for (int q = 0; q < 4; ++q) {
      float v = Sp[mf][q];
      v += __shfl_xor(v, 1); v += __shfl_xor(v, 2);
      v += __shfl_xor(v, 4); v += __shfl_xor(v, 8);
      Sp[mf][q] = v;
    }
  if (l15 == 0) {
#pragma unroll
    for (int mf = 0; mf < 4; ++mf)
#pragma unroll
      for (int q = 0; q < 4; ++q)
        atomicAdd(&S[m0 + mf * 16 + l4 * 4 + q], Sp[mf][q]);
  }
}

// ---------------------------------------------------------------------------
// Kernel 3: loss = mean_i [ log(S_i - diagsub_i) - Pterm_i ]
// ---------------------------------------------------------------------------
__global__ __launch_bounds__(256) void finalize_kernel(
    const float* __restrict__ S, const float* __restrict__ Pterm,
    const float* __restrict__ diagsub, float* __restrict__ out)
{
  const int tid = threadIdx.x;
  float acc = 0.0f;
  for (int i = tid; i < NROWS; i += 256) {
    float v = S[i] - diagsub[i];
    acc += logf(fmaxf(v, 1e-20f)) - Pterm[i];
  }
#pragma unroll
  for (int m = 1; m < 64; m <<= 1) acc += __shfl_xor(acc, m);
  __shared__ float w[4];
  if ((tid & 63) == 0) w[tid >> 6] = acc;
  __syncthreads();
  if (tid == 0) out[0] = (w[0] + w[1] + w[2] + w[3]) * (1.0f / (float)NROWS);
}

// ---------------------------------------------------------------------------
extern "C" void kernel_launch(void* const* d_in, const int* in_sizes, int n_in,
                              void* d_out, int out_size, void* d_ws, size_t ws_size,
                              hipStream_t stream) {
  const float* h  = (const float*)d_in[0];
  const float* hg = (const float*)d_in[1];

  char* ws = (char*)d_ws;
  const size_t OFF_QS   = 0;                      // 2 MB (8192*256 fp8)
  const size_t OFF_KEYS = (size_t)2 << 20;        // 4 MB (16384*256 fp8)
  const size_t OFF_P    = (size_t)6 << 20;        // 32 KB
  const size_t OFF_DIAG = OFF_P + 32 * 1024;      // 32 KB
  const size_t OFF_S    = OFF_DIAG + 32 * 1024;   // 32 KB
  const size_t NEED     = OFF_S + 32 * 1024;
  if (ws_size < NEED) return;

  unsigned int* qs8   = (unsigned int*)(ws + OFF_QS);
  unsigned int* keys8 = (unsigned int*)(ws + OFF_KEYS);
  float* Pterm   = (float*)(ws + OFF_P);
  float* diagsub = (float*)(ws + OFF_DIAG);
  float* S       = (float*)(ws + OFF_S);

  prep_kernel<<<2048, 256, 0, stream>>>(h, hg, qs8, keys8, Pterm, diagsub, S);
  nce_gemm<<<256, 512, 0, stream>>>(qs8, keys8, S);
  finalize_kernel<<<1, 256, 0, stream>>>(S, Pterm, diagsub, (float*)d_out);
}